// Round 7
// baseline (2550.778 us; speedup 1.0000x reference)
//
#include <hip/hip_runtime.h>
#include <hip/hip_bf16.h>
#include <math.h>

// ---------------------------------------------------------------------------
// Block5: LN1 -> qkv GEMM -> axial attention (m & n) -> mix -> proj(+resid)
//         -> LN2 -> fc1(+GELU) -> fc2(+resid)
// B=256 N=49 M=4 C=768 h=12 c=64 Cf=3072 -> T=50176 tokens.
// R7 changes vs R6 (both aimed at the SIGABRT):
//   (a) adaptive chunk size CB in {64..1} -> ws floor 15.7 MB (H1: tiny ws)
//   (b) GEMM staging via reg + ds_write_b128 instead of global_load_lds
//       (H2: the one exotic instruction is removed)
//   (c) GEMM handles arbitrary M (row-clamped staging, predicated stores)
// x2 (fp32 residual) lives in d_out. xln/xn/y share one buffer.
// ---------------------------------------------------------------------------

typedef __attribute__((ext_vector_type(8))) short short8;   // 8 x bf16 = 4 VGPR
typedef __attribute__((ext_vector_type(4))) float floatx4;  // MFMA acc

__device__ __forceinline__ float bf2f(unsigned short s) {
    union { float f; unsigned u; } z; z.u = ((unsigned)s) << 16; return z.f;
}
__device__ __forceinline__ unsigned short f2bf(float f) {
    union { float f; unsigned u; } z; z.f = f;
    unsigned r = z.u + 0x7fffu + ((z.u >> 16) & 1u);   // RNE
    return (unsigned short)(r >> 16);
}

// ---------------------------------------------------------------------------
// Fused fp32 -> bf16 weight conversion, all four weight tensors, float4/ushort4.
// Segment boundaries in float4 units: 442368 | 147456 | 589824 | 589824.
// ---------------------------------------------------------------------------
__global__ __launch_bounds__(256) void cvt4_kernel(const float4* __restrict__ s0,
                                                   const float4* __restrict__ s1,
                                                   const float4* __restrict__ s2,
                                                   const float4* __restrict__ s3,
                                                   ushort4* __restrict__ d0,
                                                   ushort4* __restrict__ d1,
                                                   ushort4* __restrict__ d2,
                                                   ushort4* __restrict__ d3) {
    int i = blockIdx.x * 256 + threadIdx.x;
    const float4* s; ushort4* d; int off;
    if (i < 442368)       { s = s0; d = d0; off = i; }
    else if (i < 589824)  { s = s1; d = d1; off = i - 442368; }
    else if (i < 1179648) { s = s2; d = d2; off = i - 589824; }
    else                  { s = s3; d = d3; off = i - 1179648; }
    const float4 v = s[off];
    ushort4 o;
    o.x = f2bf(v.x); o.y = f2bf(v.y); o.z = f2bf(v.z); o.w = f2bf(v.w);
    d[off] = o;
}

// ---------------------------------------------------------------------------
// LayerNorm over C=768, fp32 in -> bf16 out. One block (192 thr) per token.
// ---------------------------------------------------------------------------
__global__ __launch_bounds__(192) void ln_kernel(const float* __restrict__ x,
                                                 const float* __restrict__ g,
                                                 const float* __restrict__ b,
                                                 unsigned short* __restrict__ out) {
    const int tid = threadIdx.x;
    const size_t base = (size_t)blockIdx.x * 768 + tid * 4;
    const float4 v = *(const float4*)(x + base);
    float s  = v.x + v.y + v.z + v.w;
    float s2 = v.x * v.x + v.y * v.y + v.z * v.z + v.w * v.w;
#pragma unroll
    for (int off = 32; off; off >>= 1) { s += __shfl_xor(s, off); s2 += __shfl_xor(s2, off); }
    __shared__ float red[6];
    const int wave = tid >> 6, lane = tid & 63;
    if (lane == 0) { red[wave] = s; red[wave + 3] = s2; }
    __syncthreads();
    s  = red[0] + red[1] + red[2];
    s2 = red[3] + red[4] + red[5];
    const float mu  = s * (1.0f / 768.0f);
    const float inv = rsqrtf(s2 * (1.0f / 768.0f) - mu * mu + 1e-5f);
    const float4 gv = *(const float4*)(g + tid * 4);
    const float4 bv = *(const float4*)(b + tid * 4);
    ushort4 o;
    o.x = f2bf((v.x - mu) * inv * gv.x + bv.x);
    o.y = f2bf((v.y - mu) * inv * gv.y + bv.y);
    o.z = f2bf((v.z - mu) * inv * gv.z + bv.z);
    o.w = f2bf((v.w - mu) * inv * gv.w + bv.w);
    *(ushort4*)(out + base) = o;
}

// ---------------------------------------------------------------------------
// GEMM: out[M x N] = A[M x K] * B[N x K]^T (+ epilogue). A,B bf16 row-major.
// 128x128 tile, BK=32, 4 waves (2x2), 4x4 16x16x32 MFMA frags.
// Staging: reg (short8 global load) -> ds_write_b128, linear LDS layout.
// M arbitrary (row-clamped staging, predicated stores); N % 128 == 0.
// EPI: 0 = store bf16; 1 = +bias +resid -> fp32; 2 = +bias, GELU -> bf16
// ---------------------------------------------------------------------------
template <int EPI>
__global__ __launch_bounds__(256, 2)
void gemm_bt(const unsigned short* __restrict__ A,
             const unsigned short* __restrict__ B,
             const float* __restrict__ bias,
             const float* __restrict__ resid,
             unsigned short* __restrict__ outB,
             float* __restrict__ outF,
             int M, int N, int K) {
    __shared__ __attribute__((aligned(16))) unsigned short As[128 * 32];
    __shared__ __attribute__((aligned(16))) unsigned short Bs[128 * 32];
    const int tid  = threadIdx.x;
    const int lane = tid & 63, wave = tid >> 6;
    const int wr = wave >> 1, wc = wave & 1;          // 2x2 wave grid, each 64x64 out
    // m204 bijective XCD swizzle (valid for ANY gridDim.x)
    const int nwg = gridDim.x;
    const int q8 = nwg >> 3, r8 = nwg & 7;
    const int xcd = blockIdx.x & 7, loc = blockIdx.x >> 3;
    const int wgid = (xcd < r8 ? xcd * (q8 + 1) : r8 * (q8 + 1) + (xcd - r8) * q8) + loc;
    const int tileN = N >> 7;
    const int bx = wgid % tileN;
    const int by = wgid / tileN;
    const size_t row0 = (size_t)by << 7;
    const int col0 = bx << 7;

    floatx4 acc[4][4];
#pragma unroll
    for (int i = 0; i < 4; ++i)
#pragma unroll
        for (int j = 0; j < 4; ++j) acc[i][j] = (floatx4)(0.0f);

    const int c8  = (lane & 3) << 3;            // k-offset (elements) within row
    const int rA0 = (wave << 5) + (lane >> 2);  // staging row base for this thread
    const int ldsOff0 = (wave * 2) * 512 + lane * 8;  // thread's LDS write slot (elems)

    for (int k0 = 0; k0 < K; k0 += 32) {
        // load next tile to regs (no LDS touch -> overlaps previous reads)
        short8 ta[2], tb[2];
#pragma unroll
        for (int j = 0; j < 2; ++j) {
            const size_t rA = row0 + rA0 + j * 16;
            const size_t ra = (rA < (size_t)M) ? rA : (size_t)(M - 1);   // clamp tail
            ta[j] = *(const short8*)(A + ra * K + k0 + c8);
            tb[j] = *(const short8*)(B + (size_t)(col0 + rA0 + j * 16) * K + k0 + c8);
        }
        __syncthreads();   // all waves done READING previous tile
#pragma unroll
        for (int j = 0; j < 2; ++j) {
            *(short8*)(As + ldsOff0 + j * 512) = ta[j];
            *(short8*)(Bs + ldsOff0 + j * 512) = tb[j];
        }
        __syncthreads();   // staging visible
        short8 af[4], bfv[4];
        const int lr = lane & 15, lk = (lane >> 4) << 3;
#pragma unroll
        for (int mi = 0; mi < 4; ++mi)
            af[mi] = *(const short8*)(As + ((wr << 6) + (mi << 4) + lr) * 32 + lk);
#pragma unroll
        for (int ni = 0; ni < 4; ++ni)
            bfv[ni] = *(const short8*)(Bs + ((wc << 6) + (ni << 4) + lr) * 32 + lk);
#pragma unroll
        for (int mi = 0; mi < 4; ++mi)
#pragma unroll
            for (int ni = 0; ni < 4; ++ni)
                acc[mi][ni] = __builtin_amdgcn_mfma_f32_16x16x32_bf16(af[mi], bfv[ni], acc[mi][ni], 0, 0, 0);
    }

    // epilogue: C/D layout col = lane&15, row = (lane>>4)*4 + reg  [m89-verified]
    const int er = (lane >> 4) << 2;
    const int ec = lane & 15;
#pragma unroll
    for (int mi = 0; mi < 4; ++mi)
#pragma unroll
        for (int ni = 0; ni < 4; ++ni)
#pragma unroll
            for (int r = 0; r < 4; ++r) {
                const size_t row = row0 + (wr << 6) + (mi << 4) + er + r;
                if (row >= (size_t)M) continue;
                const int col = col0 + (wc << 6) + (ni << 4) + ec;
                const size_t o = row * N + col;
                float v = acc[mi][ni][r];
                if constexpr (EPI == 0) {
                    outB[o] = f2bf(v);
                } else if constexpr (EPI == 1) {
                    outF[o] = v + bias[col] + resid[o];
                } else {
                    float hh = v + bias[col];
                    outB[o] = f2bf(0.5f * hh * (1.0f + erff(hh * 0.70710678118654752f)));
                }
            }
}

// ---------------------------------------------------------------------------
// Attention along n (seq=49). Block = (b_local, m, head), 256 thr. q,k,v fp32
// in LDS (stride 65). One wave per row, shuffle softmax. Local to a chunk.
// ---------------------------------------------------------------------------
__global__ __launch_bounds__(256) void attn_n_kernel(const unsigned short* __restrict__ qkv,
                                                     unsigned short* __restrict__ xn) {
    __shared__ float qs[49 * 65], ks[49 * 65], vs[49 * 65];
    const int tid = threadIdx.x, lane = tid & 63, wave = tid >> 6;
    const int hh = blockIdx.x % 12;
    const int bm = blockIdx.x / 12;
    const int m = bm & 3, b = bm >> 2;   // b is chunk-local

    for (int i = tid; i < 49 * 64; i += 256) {
        const int n = i >> 6, cc = i & 63;
        const size_t base = ((size_t)(b * 49 + n) * 4 + m) * 2304 + hh * 64 + cc;
        qs[n * 65 + cc] = bf2f(qkv[base]);
        ks[n * 65 + cc] = bf2f(qkv[base + 768]);
        vs[n * 65 + cc] = bf2f(qkv[base + 1536]);
    }
    __syncthreads();

    for (int r = wave; r < 49; r += 4) {
        float s = -INFINITY;
        if (lane < 49) {
            float acc = 0.f;
            const float* q = qs + r * 65;
            const float* k = ks + lane * 65;
#pragma unroll
            for (int cc = 0; cc < 64; ++cc) acc += q[cc] * k[cc];
            s = acc * 0.125f;  // c^-0.5
        }
        float mx = s;
#pragma unroll
        for (int off = 32; off; off >>= 1) mx = fmaxf(mx, __shfl_xor(mx, off));
        const float e = (lane < 49) ? expf(s - mx) : 0.f;
        float sum = e;
#pragma unroll
        for (int off = 32; off; off >>= 1) sum += __shfl_xor(sum, off);
        const float a = e / sum;
        float o = 0.f;
        for (int j = 0; j < 49; ++j) {
            const float aj = __shfl(a, j);
            o += aj * vs[j * 65 + lane];
        }
        xn[((size_t)(b * 49 + r) * 4 + m) * 768 + hh * 64 + lane] = f2bf(o);
    }
}

// ---------------------------------------------------------------------------
// Attention along m (seq=4) + mix fusion. Block = (b_local, n), 256 thr.
// xn <- xn*w0 + x_m*w1 in place (w = softmax(mix)). Runs AFTER attn_n.
// ---------------------------------------------------------------------------
__global__ __launch_bounds__(256) void attn_m_kernel(const unsigned short* __restrict__ qkv,
                                                     const float* __restrict__ mixp,
                                                     unsigned short* __restrict__ xn) {
    __shared__ float qs[4 * 12 * 65], ks[4 * 12 * 65], vs[4 * 12 * 65];
    __shared__ float as[192];
    const int tid = threadIdx.x;
    const size_t tbase = (size_t)blockIdx.x * 4;
    const int n = blockIdx.x % 49;   // global n (independent of batch)

    for (int i = tid; i < 3072; i += 256) {
        const int m = i / 768;
        const int d = i - m * 768;
        const int slot = (m * 12 + (d >> 6)) * 65 + (d & 63);
        const size_t base = (tbase + m) * 2304 + d;
        qs[slot] = bf2f(qkv[base]);
        ks[slot] = bf2f(qkv[base + 768]);
        vs[slot] = bf2f(qkv[base + 1536]);
    }
    __syncthreads();

    if (tid < 192) {  // one score (head, m, p) per thread
        const int hh = tid >> 4, m = (tid >> 2) & 3, p = tid & 3;
        const float* q = qs + (m * 12 + hh) * 65;
        const float* k = ks + (p * 12 + hh) * 65;
        float s = 0.f;
#pragma unroll
        for (int cc = 0; cc < 64; ++cc) s += q[cc] * k[cc];
        as[tid] = s * 0.125f;
    }
    __syncthreads();
    if (tid < 48) {  // softmax over p=4 for (head, m)
        float* a = as + tid * 4;
        float mx = fmaxf(fmaxf(a[0], a[1]), fmaxf(a[2], a[3]));
        float e0 = expf(a[0] - mx), e1 = expf(a[1] - mx), e2 = expf(a[2] - mx), e3 = expf(a[3] - mx);
        float inv = 1.f / (e0 + e1 + e2 + e3);
        a[0] = e0 * inv; a[1] = e1 * inv; a[2] = e2 * inv; a[3] = e3 * inv;
    }
    __syncthreads();

    float w0[4], w1[4];
#pragma unroll
    for (int m = 0; m < 4; ++m) {
        const float m0 = mixp[(n * 4 + m) * 2], m1 = mixp[(n * 4 + m) * 2 + 1];
        const float mx = fmaxf(m0, m1);
        const float e0 = expf(m0 - mx), e1 = expf(m1 - mx);
        w0[m] = e0 / (e0 + e1);
        w1[m] = 1.0f - w0[m];
    }

    for (int o = tid; o < 3072; o += 256) {
        const int cc = o & 63, m = (o >> 6) & 3, hh = o >> 8;
        const float* a = as + hh * 16 + m * 4;
        float r = a[0] * vs[(0 * 12 + hh) * 65 + cc] + a[1] * vs[(1 * 12 + hh) * 65 + cc]
                + a[2] * vs[(2 * 12 + hh) * 65 + cc] + a[3] * vs[(3 * 12 + hh) * 65 + cc];
        const size_t oidx = (tbase + m) * 768 + hh * 64 + cc;
        const float vn = bf2f(xn[oidx]);
        xn[oidx] = f2bf(vn * w0[m] + r * w1[m]);
    }
}

// ---------------------------------------------------------------------------
extern "C" void kernel_launch(void* const* d_in, const int* in_sizes, int n_in,
                              void* d_out, int out_size, void* d_ws, size_t ws_size,
                              hipStream_t stream) {
    const float* x      = (const float*)d_in[0];
    const float* ln1_g  = (const float*)d_in[1];
    const float* ln1_b  = (const float*)d_in[2];
    const float* w_qkv  = (const float*)d_in[3];
    const float* w_proj = (const float*)d_in[4];
    const float* b_proj = (const float*)d_in[5];
    const float* mixp   = (const float*)d_in[6];
    const float* ln2_g  = (const float*)d_in[7];
    const float* ln2_b  = (const float*)d_in[8];
    const float* w_fc1  = (const float*)d_in[9];
    const float* b_fc1  = (const float*)d_in[10];
    const float* w_fc2  = (const float*)d_in[11];
    const float* b_fc2  = (const float*)d_in[12];
    float* out = (float*)d_out;

    char* ws = (char*)d_ws;
    // fixed weight area: 14,155,776 bytes
    unsigned short* wqkv_bf  = (unsigned short*)(ws);                  //  3,538,944
    unsigned short* wproj_bf = (unsigned short*)(ws + 3538944);        //  1,179,648
    unsigned short* wfc1_bf  = (unsigned short*)(ws + 4718592);        //  4,718,592
    unsigned short* wfc2_bf  = (unsigned short*)(ws + 9437184);        //  4,718,592

    // adaptive chunking: CB batches/chunk, halve until it fits ws.
    // ws need: 14,155,776 + CB*196*7680 bytes. Floor (CB=1): 15.66 MB.
    int CB = 64;
    while (CB > 1 && 14155776ull + (size_t)CB * 196 * 7680 > ws_size) CB >>= 1;
    const int nch = 256 / CB;
    const int TC = CB * 196;                  // tokens per chunk
    const int rowT = (TC + 127) >> 7;         // 128-row tiles per chunk
    unsigned short* xbuf  = (unsigned short*)(ws + 14155776);               // xln/xn/y shared
    unsigned short* qkv_c = (unsigned short*)(ws + 14155776 + (size_t)TC * 1536);  // qkv, then h

    dim3 blk(256);
    // all four weight tensors -> bf16 in one launch (1769472 float4 lanes)
    cvt4_kernel<<<6912, blk, 0, stream>>>((const float4*)w_qkv, (const float4*)w_proj,
                                          (const float4*)w_fc1, (const float4*)w_fc2,
                                          (ushort4*)wqkv_bf, (ushort4*)wproj_bf,
                                          (ushort4*)wfc1_bf, (ushort4*)wfc2_bf);

    for (int i = 0; i < nch; ++i) {
        const size_t r0 = (size_t)i * TC;
        const float* xc = x + r0 * 768;     // input residual rows
        float* x2c = out + r0 * 768;        // fp32 residual x2 lives in d_out

        ln_kernel<<<TC, dim3(192), 0, stream>>>(xc, ln1_g, ln1_b, xbuf);
        // qkv_c = xbuf @ w_qkv^T   (TC x 2304, K=768)
        gemm_bt<0><<<rowT * 18, blk, 0, stream>>>(xbuf, wqkv_bf, nullptr, nullptr, qkv_c, nullptr, TC, 2304, 768);
        // xbuf dead; attn writes xn into xbuf
        attn_n_kernel<<<CB * 48, blk, 0, stream>>>(qkv_c, xbuf);
        attn_m_kernel<<<CB * 49, blk, 0, stream>>>(qkv_c, mixp, xbuf);   // fuses mix
        // x2 = xn @ w_proj^T + b_proj + x   (fp32, into d_out rows)
        gemm_bt<1><<<rowT * 6, blk, 0, stream>>>(xbuf, wproj_bf, b_proj, xc, nullptr, x2c, TC, 768, 768);
        ln_kernel<<<TC, dim3(192), 0, stream>>>(x2c, ln2_g, ln2_b, xbuf);   // y_c (xn dead)
        // h_c = gelu(y_c @ w_fc1^T + b_fc1)  (TC x 3072), into qkv_c space
        gemm_bt<2><<<rowT * 24, blk, 0, stream>>>(xbuf, wfc1_bf, b_fc1, nullptr, qkv_c, nullptr, TC, 3072, 768);
        // out rows = h_c @ w_fc2^T + b_fc2 + x2  (K=3072)
        gemm_bt<1><<<rowT * 6, blk, 0, stream>>>(qkv_c, wfc2_bf, b_fc2, x2c, nullptr, x2c, TC, 768, 3072);
    }
}

// Round 8
// 1926.708 us; speedup vs baseline: 1.3239x; 1.3239x over previous
//
#include <hip/hip_runtime.h>
#include <hip/hip_bf16.h>
#include <math.h>

// ---------------------------------------------------------------------------
// Block5: LN1 -> qkv GEMM -> axial attention (m & n) -> mix -> proj(+resid)
//         -> LN2 -> fc1(+GELU) -> fc2(+resid)
// B=256 N=49 M=4 C=768 h=12 c=64 Cf=3072 -> T=50176 tokens.
// R8 changes vs R7 (counter-driven):
//   - attn_n rewritten with MFMA: 1 wave per (b,m,h), Q/K frags direct from
//     global, V^T + P staged in per-wave LDS (stride 72, XOR-swizzled V^T),
//     no __syncthreads at all. Was 4x187us at MfmaUtil=0 (29% of runtime).
//   - attn_m staging vectorized (ushort8 + float4 LDS writes, stride 68).
//   - global_load_lds NOT used anywhere (R6-vs-R7 isolated it as the
//     SIGABRT cause in this container; reg-staging is proven).
// ---------------------------------------------------------------------------

typedef __attribute__((ext_vector_type(8))) short short8;   // 8 x bf16 = 4 VGPR
typedef __attribute__((ext_vector_type(4))) float floatx4;  // MFMA acc

__device__ __forceinline__ float bf2f(unsigned short s) {
    union { float f; unsigned u; } z; z.u = ((unsigned)s) << 16; return z.f;
}
__device__ __forceinline__ unsigned short f2bf(float f) {
    union { float f; unsigned u; } z; z.f = f;
    unsigned r = z.u + 0x7fffu + ((z.u >> 16) & 1u);   // RNE
    return (unsigned short)(r >> 16);
}

// ---------------------------------------------------------------------------
// Fused fp32 -> bf16 weight conversion, all four weight tensors, float4/ushort4.
// ---------------------------------------------------------------------------
__global__ __launch_bounds__(256) void cvt4_kernel(const float4* __restrict__ s0,
                                                   const float4* __restrict__ s1,
                                                   const float4* __restrict__ s2,
                                                   const float4* __restrict__ s3,
                                                   ushort4* __restrict__ d0,
                                                   ushort4* __restrict__ d1,
                                                   ushort4* __restrict__ d2,
                                                   ushort4* __restrict__ d3) {
    int i = blockIdx.x * 256 + threadIdx.x;
    const float4* s; ushort4* d; int off;
    if (i < 442368)       { s = s0; d = d0; off = i; }
    else if (i < 589824)  { s = s1; d = d1; off = i - 442368; }
    else if (i < 1179648) { s = s2; d = d2; off = i - 589824; }
    else                  { s = s3; d = d3; off = i - 1179648; }
    const float4 v = s[off];
    ushort4 o;
    o.x = f2bf(v.x); o.y = f2bf(v.y); o.z = f2bf(v.z); o.w = f2bf(v.w);
    d[off] = o;
}

// ---------------------------------------------------------------------------
// LayerNorm over C=768, fp32 in -> bf16 out. One block (192 thr) per token.
// ---------------------------------------------------------------------------
__global__ __launch_bounds__(192) void ln_kernel(const float* __restrict__ x,
                                                 const float* __restrict__ g,
                                                 const float* __restrict__ b,
                                                 unsigned short* __restrict__ out) {
    const int tid = threadIdx.x;
    const size_t base = (size_t)blockIdx.x * 768 + tid * 4;
    const float4 v = *(const float4*)(x + base);
    float s  = v.x + v.y + v.z + v.w;
    float s2 = v.x * v.x + v.y * v.y + v.z * v.z + v.w * v.w;
#pragma unroll
    for (int off = 32; off; off >>= 1) { s += __shfl_xor(s, off); s2 += __shfl_xor(s2, off); }
    __shared__ float red[6];
    const int wave = tid >> 6, lane = tid & 63;
    if (lane == 0) { red[wave] = s; red[wave + 3] = s2; }
    __syncthreads();
    s  = red[0] + red[1] + red[2];
    s2 = red[3] + red[4] + red[5];
    const float mu  = s * (1.0f / 768.0f);
    const float inv = rsqrtf(s2 * (1.0f / 768.0f) - mu * mu + 1e-5f);
    const float4 gv = *(const float4*)(g + tid * 4);
    const float4 bv = *(const float4*)(b + tid * 4);
    ushort4 o;
    o.x = f2bf((v.x - mu) * inv * gv.x + bv.x);
    o.y = f2bf((v.y - mu) * inv * gv.y + bv.y);
    o.z = f2bf((v.z - mu) * inv * gv.z + bv.z);
    o.w = f2bf((v.w - mu) * inv * gv.w + bv.w);
    *(ushort4*)(out + base) = o;
}

// ---------------------------------------------------------------------------
// GEMM: out[M x N] = A[M x K] * B[N x K]^T (+ epilogue). A,B bf16 row-major.
// 128x128 tile, BK=32, 4 waves (2x2), 4x4 16x16x32 MFMA frags.
// Staging: reg (short8 global load) -> ds_write_b128, linear LDS layout.
// EPI: 0 = store bf16; 1 = +bias +resid -> fp32; 2 = +bias, GELU -> bf16
// ---------------------------------------------------------------------------
template <int EPI>
__global__ __launch_bounds__(256, 2)
void gemm_bt(const unsigned short* __restrict__ A,
             const unsigned short* __restrict__ B,
             const float* __restrict__ bias,
             const float* __restrict__ resid,
             unsigned short* __restrict__ outB,
             float* __restrict__ outF,
             int M, int N, int K) {
    __shared__ __attribute__((aligned(16))) unsigned short As[128 * 32];
    __shared__ __attribute__((aligned(16))) unsigned short Bs[128 * 32];
    const int tid  = threadIdx.x;
    const int lane = tid & 63, wave = tid >> 6;
    const int wr = wave >> 1, wc = wave & 1;          // 2x2 wave grid, each 64x64 out
    const int nwg = gridDim.x;
    const int q8 = nwg >> 3, r8 = nwg & 7;
    const int xcd = blockIdx.x & 7, loc = blockIdx.x >> 3;
    const int wgid = (xcd < r8 ? xcd * (q8 + 1) : r8 * (q8 + 1) + (xcd - r8) * q8) + loc;
    const int tileN = N >> 7;
    const int bx = wgid % tileN;
    const int by = wgid / tileN;
    const size_t row0 = (size_t)by << 7;
    const int col0 = bx << 7;

    floatx4 acc[4][4];
#pragma unroll
    for (int i = 0; i < 4; ++i)
#pragma unroll
        for (int j = 0; j < 4; ++j) acc[i][j] = (floatx4)(0.0f);

    const int c8  = (lane & 3) << 3;            // k-offset (elements) within row
    const int rA0 = (wave << 5) + (lane >> 2);  // staging row base for this thread
    const int ldsOff0 = (wave * 2) * 512 + lane * 8;  // thread's LDS write slot (elems)

    for (int k0 = 0; k0 < K; k0 += 32) {
        short8 ta[2], tb[2];
#pragma unroll
        for (int j = 0; j < 2; ++j) {
            const size_t rA = row0 + rA0 + j * 16;
            const size_t ra = (rA < (size_t)M) ? rA : (size_t)(M - 1);   // clamp tail
            ta[j] = *(const short8*)(A + ra * K + k0 + c8);
            tb[j] = *(const short8*)(B + (size_t)(col0 + rA0 + j * 16) * K + k0 + c8);
        }
        __syncthreads();   // all waves done READING previous tile
#pragma unroll
        for (int j = 0; j < 2; ++j) {
            *(short8*)(As + ldsOff0 + j * 512) = ta[j];
            *(short8*)(Bs + ldsOff0 + j * 512) = tb[j];
        }
        __syncthreads();   // staging visible
        short8 af[4], bfv[4];
        const int lr = lane & 15, lk = (lane >> 4) << 3;
#pragma unroll
        for (int mi = 0; mi < 4; ++mi)
            af[mi] = *(const short8*)(As + ((wr << 6) + (mi << 4) + lr) * 32 + lk);
#pragma unroll
        for (int ni = 0; ni < 4; ++ni)
            bfv[ni] = *(const short8*)(Bs + ((wc << 6) + (ni << 4) + lr) * 32 + lk);
#pragma unroll
        for (int mi = 0; mi < 4; ++mi)
#pragma unroll
            for (int ni = 0; ni < 4; ++ni)
                acc[mi][ni] = __builtin_amdgcn_mfma_f32_16x16x32_bf16(af[mi], bfv[ni], acc[mi][ni], 0, 0, 0);
    }

    const int er = (lane >> 4) << 2;
    const int ec = lane & 15;
#pragma unroll
    for (int mi = 0; mi < 4; ++mi)
#pragma unroll
        for (int ni = 0; ni < 4; ++ni)
#pragma unroll
            for (int r = 0; r < 4; ++r) {
                const size_t row = row0 + (wr << 6) + (mi << 4) + er + r;
                if (row >= (size_t)M) continue;
                const int col = col0 + (wc << 6) + (ni << 4) + ec;
                const size_t o = row * N + col;
                float v = acc[mi][ni][r];
                if constexpr (EPI == 0) {
                    outB[o] = f2bf(v);
                } else if constexpr (EPI == 1) {
                    outF[o] = v + bias[col] + resid[o];
                } else {
                    float hh = v + bias[col];
                    outB[o] = f2bf(0.5f * hh * (1.0f + erff(hh * 0.70710678118654752f)));
                }
            }
}

// ---------------------------------------------------------------------------
// Attention along n (seq=49), MFMA version. Block = (b_local, m, head-group),
// 4 waves, wave = one head. No cross-wave LDS -> NO barriers.
// Per wave: S = Q*K^T (32 MFMA, frags direct from global), in-reg softmax
// (C/D layout: col=lane&15, row=(lane>>4)*4+r), P -> LDS bf16 [64][72],
// V^T -> LDS bf16 [64][72] XOR-swizzled, O = P*V (32 MFMA), store rows<49.
// ---------------------------------------------------------------------------
__global__ __launch_bounds__(256) void attn_n_kernel(const unsigned short* __restrict__ qkv,
                                                     unsigned short* __restrict__ xn) {
    __shared__ __attribute__((aligned(16))) unsigned short lds[4 * 9216];
    const int tid = threadIdx.x, lane = tid & 63, wave = tid >> 6;
    const int hg = blockIdx.x % 3;
    const int bm = blockIdx.x / 3;
    const int m = bm & 3, b = bm >> 2;    // b chunk-local
    const int h = hg * 4 + wave;
    const int lr = lane & 15, hi = lane >> 4;
    unsigned short* Ps  = lds + wave * 9216;   // P  [64][72]
    unsigned short* vsT = Ps + 4608;           // V^T[64][72], XOR-swizzled

    // ---- stage V^T (bf16, swizzle: p ^ ((cc>>3)<<3) -> conflict-free writes)
    for (int c = lane; c < 392; c += 64) {     // 392 chunks = 49 rows x 8
        const int p = c >> 3, cc0 = (c & 7) << 3;
        const size_t vb = ((size_t)((b * 49 + p) * 4 + m)) * 2304 + 1536 + h * 64 + cc0;
        const short8 v = *(const short8*)(qkv + vb);
#pragma unroll
        for (int j = 0; j < 8; ++j) {
            const int cc = cc0 + j;
            vsT[cc * 72 + (p ^ ((cc >> 3) << 3))] = (unsigned short)v[j];
        }
    }
#pragma unroll
    for (int it = 0; it < 15; ++it) {          // zero-pad p = 49..63 (NaN guard)
        const int cc = lane, p = 49 + it;
        vsT[cc * 72 + (p ^ ((cc >> 3) << 3))] = 0;
    }

    // ---- S = Q*K^T: fragments straight from global (rows are 16B-contig) ----
    short8 qf[4][2], kf[4][2];
#pragma unroll
    for (int mi = 0; mi < 4; ++mi) {
        int q = mi * 16 + lr; q = (q > 48) ? 48 : q;          // clamp pad rows
        const size_t qb = ((size_t)((b * 49 + q) * 4 + m)) * 2304 + h * 64;
#pragma unroll
        for (int ks = 0; ks < 2; ++ks) {
            qf[mi][ks] = *(const short8*)(qkv + qb + ks * 32 + hi * 8);
            kf[mi][ks] = *(const short8*)(qkv + qb + 768 + ks * 32 + hi * 8);
        }
    }
    floatx4 acc[4][4];
#pragma unroll
    for (int i = 0; i < 4; ++i)
#pragma unroll
        for (int j = 0; j < 4; ++j) acc[i][j] = (floatx4)(0.0f);
#pragma unroll
    for (int ks = 0; ks < 2; ++ks)
#pragma unroll
        for (int mi = 0; mi < 4; ++mi)
#pragma unroll
            for (int ni = 0; ni < 4; ++ni)
                acc[mi][ni] = __builtin_amdgcn_mfma_f32_16x16x32_bf16(qf[mi][ks], kf[ni][ks], acc[mi][ni], 0, 0, 0);

    // ---- mask + scale, row softmax (row = mi*16+hi*4+r, col = ni*16+lr) ----
#pragma unroll
    for (int mi = 0; mi < 4; ++mi)
#pragma unroll
        for (int ni = 0; ni < 4; ++ni) {
            const int col = ni * 16 + lr;
#pragma unroll
            for (int r = 0; r < 4; ++r)
                acc[mi][ni][r] = (col < 49) ? acc[mi][ni][r] * 0.125f : -1e30f;
        }
#pragma unroll
    for (int mi = 0; mi < 4; ++mi) {
#pragma unroll
        for (int r = 0; r < 4; ++r) {
            float mx = fmaxf(fmaxf(acc[mi][0][r], acc[mi][1][r]), fmaxf(acc[mi][2][r], acc[mi][3][r]));
#pragma unroll
            for (int off = 8; off; off >>= 1) mx = fmaxf(mx, __shfl_xor(mx, off));
            float e0 = expf(acc[mi][0][r] - mx), e1 = expf(acc[mi][1][r] - mx);
            float e2 = expf(acc[mi][2][r] - mx), e3 = expf(acc[mi][3][r] - mx);
            float sum = e0 + e1 + e2 + e3;
#pragma unroll
            for (int off = 8; off; off >>= 1) sum += __shfl_xor(sum, off);
            const float inv = 1.0f / sum;
            const int row = mi * 16 + hi * 4 + r;
            Ps[row * 72 + 0  + lr] = f2bf(e0 * inv);
            Ps[row * 72 + 16 + lr] = f2bf(e1 * inv);
            Ps[row * 72 + 32 + lr] = f2bf(e2 * inv);
            Ps[row * 72 + 48 + lr] = f2bf(e3 * inv);
        }
    }

    // ---- O = P*V via LDS fragments ----
    floatx4 oac[4][4];
#pragma unroll
    for (int i = 0; i < 4; ++i)
#pragma unroll
        for (int j = 0; j < 4; ++j) oac[i][j] = (floatx4)(0.0f);
#pragma unroll
    for (int ks = 0; ks < 2; ++ks) {
        short8 pf[4], vf[4];
        const int p0 = ks * 32 + hi * 8;
#pragma unroll
        for (int mi = 0; mi < 4; ++mi)
            pf[mi] = *(const short8*)(Ps + (mi * 16 + lr) * 72 + p0);
#pragma unroll
        for (int ni = 0; ni < 4; ++ni) {
            const int cc = ni * 16 + lr;
            vf[ni] = *(const short8*)(vsT + cc * 72 + (p0 ^ ((cc >> 3) << 3)));
        }
#pragma unroll
        for (int mi = 0; mi < 4; ++mi)
#pragma unroll
            for (int ni = 0; ni < 4; ++ni)
                oac[mi][ni] = __builtin_amdgcn_mfma_f32_16x16x32_bf16(pf[mi], vf[ni], oac[mi][ni], 0, 0, 0);
    }

    // ---- store rows < 49 ----
#pragma unroll
    for (int mi = 0; mi < 4; ++mi)
#pragma unroll
        for (int r = 0; r < 4; ++r) {
            const int row = mi * 16 + hi * 4 + r;
            if (row >= 49) continue;
            const size_t ob = ((size_t)((b * 49 + row) * 4 + m)) * 768 + h * 64;
#pragma unroll
            for (int ni = 0; ni < 4; ++ni)
                xn[ob + ni * 16 + lr] = f2bf(oac[mi][ni][r]);
        }
}

// ---------------------------------------------------------------------------
// Attention along m (seq=4) + mix fusion. Block = (b_local, n), 256 thr.
// Vectorized staging (ushort8 -> float4 LDS, stride 68). In-place xn update.
// ---------------------------------------------------------------------------
__global__ __launch_bounds__(256) void attn_m_kernel(const unsigned short* __restrict__ qkv,
                                                     const float* __restrict__ mixp,
                                                     unsigned short* __restrict__ xn) {
    __shared__ __attribute__((aligned(16))) float qs[4 * 12 * 68], ks[4 * 12 * 68], vs[4 * 12 * 68];
    __shared__ float as[192];
    const int tid = threadIdx.x;
    const size_t tbase = (size_t)blockIdx.x * 4;
    const int n = blockIdx.x % 49;   // global n (independent of batch)

    for (int c = tid; c < 384; c += 256) {   // 384 = 4m x 12h x 8 cc-chunks
        const int mq = c / 96;
        const int rem = c - mq * 96;
        const int hh = rem >> 3, cc0 = (rem & 7) << 3;
        const size_t base = (tbase + mq) * 2304 + hh * 64 + cc0;
        const short8 qv = *(const short8*)(qkv + base);
        const short8 kv = *(const short8*)(qkv + base + 768);
        const short8 vv = *(const short8*)(qkv + base + 1536);
        const int slot = (mq * 12 + hh) * 68 + cc0;
#pragma unroll
        for (int j = 0; j < 4; ++j) {
            float4 fq, fk, fv;
            (void)fq; (void)fk; (void)fv;
        }
        float4 f;
        f.x = bf2f((unsigned short)qv[0]); f.y = bf2f((unsigned short)qv[1]);
        f.z = bf2f((unsigned short)qv[2]); f.w = bf2f((unsigned short)qv[3]);
        *(float4*)(qs + slot) = f;
        f.x = bf2f((unsigned short)qv[4]); f.y = bf2f((unsigned short)qv[5]);
        f.z = bf2f((unsigned short)qv[6]); f.w = bf2f((unsigned short)qv[7]);
        *(float4*)(qs + slot + 4) = f;
        f.x = bf2f((unsigned short)kv[0]); f.y = bf2f((unsigned short)kv[1]);
        f.z = bf2f((unsigned short)kv[2]); f.w = bf2f((unsigned short)kv[3]);
        *(float4*)(ks + slot) = f;
        f.x = bf2f((unsigned short)kv[4]); f.y = bf2f((unsigned short)kv[5]);
        f.z = bf2f((unsigned short)kv[6]); f.w = bf2f((unsigned short)kv[7]);
        *(float4*)(ks + slot + 4) = f;
        f.x = bf2f((unsigned short)vv[0]); f.y = bf2f((unsigned short)vv[1]);
        f.z = bf2f((unsigned short)vv[2]); f.w = bf2f((unsigned short)vv[3]);
        *(float4*)(vs + slot) = f;
        f.x = bf2f((unsigned short)vv[4]); f.y = bf2f((unsigned short)vv[5]);
        f.z = bf2f((unsigned short)vv[6]); f.w = bf2f((unsigned short)vv[7]);
        *(float4*)(vs + slot + 4) = f;
    }
    __syncthreads();

    if (tid < 192) {  // one score (head, m, p) per thread
        const int hh = tid >> 4, m = (tid >> 2) & 3, p = tid & 3;
        const float* q = qs + (m * 12 + hh) * 68;
        const float* k = ks + (p * 12 + hh) * 68;
        float s = 0.f;
#pragma unroll
        for (int cc = 0; cc < 64; ++cc) s += q[cc] * k[cc];
        as[tid] = s * 0.125f;
    }
    __syncthreads();
    if (tid < 48) {  // softmax over p=4 for (head, m)
        float* a = as + tid * 4;
        float mx = fmaxf(fmaxf(a[0], a[1]), fmaxf(a[2], a[3]));
        float e0 = expf(a[0] - mx), e1 = expf(a[1] - mx), e2 = expf(a[2] - mx), e3 = expf(a[3] - mx);
        float inv = 1.f / (e0 + e1 + e2 + e3);
        a[0] = e0 * inv; a[1] = e1 * inv; a[2] = e2 * inv; a[3] = e3 * inv;
    }
    __syncthreads();

    float w0[4], w1[4];
#pragma unroll
    for (int m = 0; m < 4; ++m) {
        const float m0 = mixp[(n * 4 + m) * 2], m1 = mixp[(n * 4 + m) * 2 + 1];
        const float mx = fmaxf(m0, m1);
        const float e0 = expf(m0 - mx), e1 = expf(m1 - mx);
        w0[m] = e0 / (e0 + e1);
        w1[m] = 1.0f - w0[m];
    }

    for (int o = tid; o < 3072; o += 256) {
        const int cc = o & 63, m = (o >> 6) & 3, hh = o >> 8;
        const float* a = as + hh * 16 + m * 4;
        float r = a[0] * vs[(0 * 12 + hh) * 68 + cc] + a[1] * vs[(1 * 12 + hh) * 68 + cc]
                + a[2] * vs[(2 * 12 + hh) * 68 + cc] + a[3] * vs[(3 * 12 + hh) * 68 + cc];
        const size_t oidx = (tbase + m) * 768 + hh * 64 + cc;
        const float vn = bf2f(xn[oidx]);
        xn[oidx] = f2bf(vn * w0[m] + r * w1[m]);
    }
}

// ---------------------------------------------------------------------------
extern "C" void kernel_launch(void* const* d_in, const int* in_sizes, int n_in,
                              void* d_out, int out_size, void* d_ws, size_t ws_size,
                              hipStream_t stream) {
    const float* x      = (const float*)d_in[0];
    const float* ln1_g  = (const float*)d_in[1];
    const float* ln1_b  = (const float*)d_in[2];
    const float* w_qkv  = (const float*)d_in[3];
    const float* w_proj = (const float*)d_in[4];
    const float* b_proj = (const float*)d_in[5];
    const float* mixp   = (const float*)d_in[6];
    const float* ln2_g  = (const float*)d_in[7];
    const float* ln2_b  = (const float*)d_in[8];
    const float* w_fc1  = (const float*)d_in[9];
    const float* b_fc1  = (const float*)d_in[10];
    const float* w_fc2  = (const float*)d_in[11];
    const float* b_fc2  = (const float*)d_in[12];
    float* out = (float*)d_out;

    char* ws = (char*)d_ws;
    unsigned short* wqkv_bf  = (unsigned short*)(ws);                  //  3,538,944
    unsigned short* wproj_bf = (unsigned short*)(ws + 3538944);        //  1,179,648
    unsigned short* wfc1_bf  = (unsigned short*)(ws + 4718592);        //  4,718,592
    unsigned short* wfc2_bf  = (unsigned short*)(ws + 9437184);        //  4,718,592

    // adaptive chunking (proven: ws >= 110.5 MB -> CB=64, kept for safety)
    int CB = 64;
    while (CB > 1 && 14155776ull + (size_t)CB * 196 * 7680 > ws_size) CB >>= 1;
    const int nch = 256 / CB;
    const int TC = CB * 196;
    const int rowT = (TC + 127) >> 7;
    unsigned short* xbuf  = (unsigned short*)(ws + 14155776);
    unsigned short* qkv_c = (unsigned short*)(ws + 14155776 + (size_t)TC * 1536);

    dim3 blk(256);
    cvt4_kernel<<<6912, blk, 0, stream>>>((const float4*)w_qkv, (const float4*)w_proj,
                                          (const float4*)w_fc1, (const float4*)w_fc2,
                                          (ushort4*)wqkv_bf, (ushort4*)wproj_bf,
                                          (ushort4*)wfc1_bf, (ushort4*)wfc2_bf);

    for (int i = 0; i < nch; ++i) {
        const size_t r0 = (size_t)i * TC;
        const float* xc = x + r0 * 768;
        float* x2c = out + r0 * 768;

        ln_kernel<<<TC, dim3(192), 0, stream>>>(xc, ln1_g, ln1_b, xbuf);
        gemm_bt<0><<<rowT * 18, blk, 0, stream>>>(xbuf, wqkv_bf, nullptr, nullptr, qkv_c, nullptr, TC, 2304, 768);
        attn_n_kernel<<<CB * 12, blk, 0, stream>>>(qkv_c, xbuf);          // 4 heads/block
        attn_m_kernel<<<CB * 49, blk, 0, stream>>>(qkv_c, mixp, xbuf);    // fuses mix
        gemm_bt<1><<<rowT * 6, blk, 0, stream>>>(xbuf, wproj_bf, b_proj, xc, nullptr, x2c, TC, 768, 768);
        ln_kernel<<<TC, dim3(192), 0, stream>>>(x2c, ln2_g, ln2_b, xbuf);
        gemm_bt<2><<<rowT * 24, blk, 0, stream>>>(xbuf, wfc1_bf, b_fc1, nullptr, qkv_c, nullptr, TC, 3072, 768);
        gemm_bt<1><<<rowT * 6, blk, 0, stream>>>(qkv_c, wfc2_bf, b_fc2, x2c, nullptr, x2c, TC, 768, 3072);
    }
}

// Round 10
// 1922.127 us; speedup vs baseline: 1.3271x; 1.0024x over previous
//
#include <hip/hip_runtime.h>
#include <hip/hip_bf16.h>
#include <math.h>

// ---------------------------------------------------------------------------
// Block5: LN1 -> qkv GEMM -> axial attention (m & n) -> mix -> proj(+resid)
//         -> LN2 -> fc1(+GELU) -> fc2(+resid)
// B=256 N=49 M=4 C=768 h=12 c=64 Cf=3072 -> T=50176 tokens.
// R9 changes vs R8 (counter-driven: gemm_bt had 7.2M LDS bank conflicts,
// MfmaUtil 18%, VALUBusy 34% -> LDS-conflict + staging-latency bound):
//   - T2 XOR swizzle on GEMM LDS tiles: slot' = slot ^ ((row>>1)&3).
//     Read was 8-way conflicted (row stride 64B); now 2-way (free, m136).
//   - Register prefetch of tile k+1 issued before tile k's MFMAs
//     (hides L2/HBM latency under compute; was fully exposed).
// global_load_lds still banned (R6-vs-R7 isolated it as the SIGABRT cause).
// ---------------------------------------------------------------------------

typedef __attribute__((ext_vector_type(8))) short short8;   // 8 x bf16 = 4 VGPR
typedef __attribute__((ext_vector_type(4))) float floatx4;  // MFMA acc

__device__ __forceinline__ float bf2f(unsigned short s) {
    union { float f; unsigned u; } z; z.u = ((unsigned)s) << 16; return z.f;
}
__device__ __forceinline__ unsigned short f2bf(float f) {
    union { float f; unsigned u; } z; z.f = f;
    unsigned r = z.u + 0x7fffu + ((z.u >> 16) & 1u);   // RNE
    return (unsigned short)(r >> 16);
}

// ---------------------------------------------------------------------------
// Fused fp32 -> bf16 weight conversion, all four weight tensors.
// ---------------------------------------------------------------------------
__global__ __launch_bounds__(256) void cvt4_kernel(const float4* __restrict__ s0,
                                                   const float4* __restrict__ s1,
                                                   const float4* __restrict__ s2,
                                                   const float4* __restrict__ s3,
                                                   ushort4* __restrict__ d0,
                                                   ushort4* __restrict__ d1,
                                                   ushort4* __restrict__ d2,
                                                   ushort4* __restrict__ d3) {
    int i = blockIdx.x * 256 + threadIdx.x;
    const float4* s; ushort4* d; int off;
    if (i < 442368)       { s = s0; d = d0; off = i; }
    else if (i < 589824)  { s = s1; d = d1; off = i - 442368; }
    else if (i < 1179648) { s = s2; d = d2; off = i - 589824; }
    else                  { s = s3; d = d3; off = i - 1179648; }
    const float4 v = s[off];
    ushort4 o;
    o.x = f2bf(v.x); o.y = f2bf(v.y); o.z = f2bf(v.z); o.w = f2bf(v.w);
    d[off] = o;
}

// ---------------------------------------------------------------------------
// LayerNorm over C=768, fp32 in -> bf16 out. One block (192 thr) per token.
// ---------------------------------------------------------------------------
__global__ __launch_bounds__(192) void ln_kernel(const float* __restrict__ x,
                                                 const float* __restrict__ g,
                                                 const float* __restrict__ b,
                                                 unsigned short* __restrict__ out) {
    const int tid = threadIdx.x;
    const size_t base = (size_t)blockIdx.x * 768 + tid * 4;
    const float4 v = *(const float4*)(x + base);
    float s  = v.x + v.y + v.z + v.w;
    float s2 = v.x * v.x + v.y * v.y + v.z * v.z + v.w * v.w;
#pragma unroll
    for (int off = 32; off; off >>= 1) { s += __shfl_xor(s, off); s2 += __shfl_xor(s2, off); }
    __shared__ float red[6];
    const int wave = tid >> 6, lane = tid & 63;
    if (lane == 0) { red[wave] = s; red[wave + 3] = s2; }
    __syncthreads();
    s  = red[0] + red[1] + red[2];
    s2 = red[3] + red[4] + red[5];
    const float mu  = s * (1.0f / 768.0f);
    const float inv = rsqrtf(s2 * (1.0f / 768.0f) - mu * mu + 1e-5f);
    const float4 gv = *(const float4*)(g + tid * 4);
    const float4 bv = *(const float4*)(b + tid * 4);
    ushort4 o;
    o.x = f2bf((v.x - mu) * inv * gv.x + bv.x);
    o.y = f2bf((v.y - mu) * inv * gv.y + bv.y);
    o.z = f2bf((v.z - mu) * inv * gv.z + bv.z);
    o.w = f2bf((v.w - mu) * inv * gv.w + bv.w);
    *(ushort4*)(out + base) = o;
}

// ---------------------------------------------------------------------------
// GEMM: out[M x N] = A[M x K] * B[N x K]^T (+ epilogue). A,B bf16 row-major.
// 128x128 tile, BK=32, 4 waves (2x2), 4x4 16x16x32 MFMA frags.
// LDS tiles XOR-swizzled (T2): elem addr = row*32 + (slot^((row>>1)&3))*8.
// Staging: reg prefetch (k+1 issued before k's MFMAs) -> ds_write_b128.
// EPI: 0 = store bf16; 1 = +bias +resid -> fp32; 2 = +bias, GELU -> bf16
// ---------------------------------------------------------------------------
template <int EPI>
__global__ __launch_bounds__(256, 2)
void gemm_bt(const unsigned short* __restrict__ A,
             const unsigned short* __restrict__ B,
             const float* __restrict__ bias,
             const float* __restrict__ resid,
             unsigned short* __restrict__ outB,
             float* __restrict__ outF,
             int M, int N, int K) {
    __shared__ __attribute__((aligned(16))) unsigned short As[128 * 32];
    __shared__ __attribute__((aligned(16))) unsigned short Bs[128 * 32];
    const int tid  = threadIdx.x;
    const int lane = tid & 63, wave = tid >> 6;
    const int wr = wave >> 1, wc = wave & 1;          // 2x2 wave grid, each 64x64 out
    const int nwg = gridDim.x;
    const int q8 = nwg >> 3, r8 = nwg & 7;
    const int xcd = blockIdx.x & 7, loc = blockIdx.x >> 3;
    const int wgid = (xcd < r8 ? xcd * (q8 + 1) : r8 * (q8 + 1) + (xcd - r8) * q8) + loc;
    const int tileN = N >> 7;
    const int bx = wgid % tileN;
    const int by = wgid / tileN;
    const size_t row0 = (size_t)by << 7;
    const int col0 = bx << 7;

    floatx4 acc[4][4];
#pragma unroll
    for (int i = 0; i < 4; ++i)
#pragma unroll
        for (int j = 0; j < 4; ++j) acc[i][j] = (floatx4)(0.0f);

    const int c8  = (lane & 3) << 3;            // k-offset (elements) within row
    const int rA0 = (wave << 5) + (lane >> 2);  // this thread's tile row (j adds 16)
    // swizzled write slot (elements): row*32 + wslot. (row>>1)&3 == (lane>>3)&3 here.
    const int wslot = (((lane & 3) ^ ((lane >> 3) & 3)) << 3);
    const int lr = lane & 15;
    // swizzled read slot offset (elements), same for A and B and all mi/ni
    const int rs = (((lane >> 4) ^ ((lr >> 1) & 3)) << 3);

    short8 ta[2], tb[2], na[2], nb[2];
#pragma unroll
    for (int j = 0; j < 2; ++j) {                       // prologue: load k0=0
        const size_t rA = row0 + rA0 + j * 16;
        const size_t ra = (rA < (size_t)M) ? rA : (size_t)(M - 1);
        ta[j] = *(const short8*)(A + ra * K + c8);
        tb[j] = *(const short8*)(B + (size_t)(col0 + rA0 + j * 16) * K + c8);
    }

    for (int k0 = 0; k0 < K; k0 += 32) {
        __syncthreads();   // all waves done READING previous tile
#pragma unroll
        for (int j = 0; j < 2; ++j) {
            *(short8*)(As + (rA0 + j * 16) * 32 + wslot) = ta[j];
            *(short8*)(Bs + (rA0 + j * 16) * 32 + wslot) = tb[j];
        }
        __syncthreads();   // staging visible
        const int kn = k0 + 32;
        if (kn < K) {      // prefetch next tile: latency hides under MFMAs
#pragma unroll
            for (int j = 0; j < 2; ++j) {
                const size_t rA = row0 + rA0 + j * 16;
                const size_t ra = (rA < (size_t)M) ? rA : (size_t)(M - 1);
                na[j] = *(const short8*)(A + ra * K + kn + c8);
                nb[j] = *(const short8*)(B + (size_t)(col0 + rA0 + j * 16) * K + kn + c8);
            }
        }
        short8 af[4], bfv[4];
#pragma unroll
        for (int mi = 0; mi < 4; ++mi)
            af[mi] = *(const short8*)(As + ((wr << 6) + (mi << 4) + lr) * 32 + rs);
#pragma unroll
        for (int ni = 0; ni < 4; ++ni)
            bfv[ni] = *(const short8*)(Bs + ((wc << 6) + (ni << 4) + lr) * 32 + rs);
#pragma unroll
        for (int mi = 0; mi < 4; ++mi)
#pragma unroll
            for (int ni = 0; ni < 4; ++ni)
                acc[mi][ni] = __builtin_amdgcn_mfma_f32_16x16x32_bf16(af[mi], bfv[ni], acc[mi][ni], 0, 0, 0);
#pragma unroll
        for (int j = 0; j < 2; ++j) { ta[j] = na[j]; tb[j] = nb[j]; }
    }

    const int er = (lane >> 4) << 2;
    const int ec = lane & 15;
#pragma unroll
    for (int mi = 0; mi < 4; ++mi)
#pragma unroll
        for (int ni = 0; ni < 4; ++ni)
#pragma unroll
            for (int r = 0; r < 4; ++r) {
                const size_t row = row0 + (wr << 6) + (mi << 4) + er + r;
                if (row >= (size_t)M) continue;
                const int col = col0 + (wc << 6) + (ni << 4) + ec;
                const size_t o = row * N + col;
                float v = acc[mi][ni][r];
                if constexpr (EPI == 0) {
                    outB[o] = f2bf(v);
                } else if constexpr (EPI == 1) {
                    outF[o] = v + bias[col] + resid[o];
                } else {
                    float hh = v + bias[col];
                    outB[o] = f2bf(0.5f * hh * (1.0f + erff(hh * 0.70710678118654752f)));
                }
            }
}

// ---------------------------------------------------------------------------
// Attention along n (seq=49), MFMA version. Block = (b_local, m, head-group),
// 4 waves, wave = one head, private LDS slice, no barriers.
// ---------------------------------------------------------------------------
__global__ __launch_bounds__(256) void attn_n_kernel(const unsigned short* __restrict__ qkv,
                                                     unsigned short* __restrict__ xn) {
    __shared__ __attribute__((aligned(16))) unsigned short lds[4 * 9216];
    const int tid = threadIdx.x, lane = tid & 63, wave = tid >> 6;
    const int hg = blockIdx.x % 3;
    const int bm = blockIdx.x / 3;
    const int m = bm & 3, b = bm >> 2;    // b chunk-local
    const int h = hg * 4 + wave;
    const int lr = lane & 15, hi = lane >> 4;
    unsigned short* Ps  = lds + wave * 9216;   // P  [64][72]
    unsigned short* vsT = Ps + 4608;           // V^T[64][72], XOR-swizzled

    // ---- stage V^T (bf16, swizzle: p ^ ((cc>>3)<<3) -> conflict-free writes)
    for (int c = lane; c < 392; c += 64) {     // 392 chunks = 49 rows x 8
        const int p = c >> 3, cc0 = (c & 7) << 3;
        const size_t vb = ((size_t)((b * 49 + p) * 4 + m)) * 2304 + 1536 + h * 64 + cc0;
        const short8 v = *(const short8*)(qkv + vb);
#pragma unroll
        for (int j = 0; j < 8; ++j) {
            const int cc = cc0 + j;
            vsT[cc * 72 + (p ^ ((cc >> 3) << 3))] = (unsigned short)v[j];
        }
    }
#pragma unroll
    for (int it = 0; it < 15; ++it) {          // zero-pad p = 49..63 (NaN guard)
        const int cc = lane, p = 49 + it;
        vsT[cc * 72 + (p ^ ((cc >> 3) << 3))] = 0;
    }

    // ---- S = Q*K^T: fragments straight from global (rows are 16B-contig) ----
    short8 qf[4][2], kf[4][2];
#pragma unroll
    for (int mi = 0; mi < 4; ++mi) {
        int q = mi * 16 + lr; q = (q > 48) ? 48 : q;          // clamp pad rows
        const size_t qb = ((size_t)((b * 49 + q) * 4 + m)) * 2304 + h * 64;
#pragma unroll
        for (int ks = 0; ks < 2; ++ks) {
            qf[mi][ks] = *(const short8*)(qkv + qb + ks * 32 + hi * 8);
            kf[mi][ks] = *(const short8*)(qkv + qb + 768 + ks * 32 + hi * 8);
        }
    }
    floatx4 acc[4][4];
#pragma unroll
    for (int i = 0; i < 4; ++i)
#pragma unroll
        for (int j = 0; j < 4; ++j) acc[i][j] = (floatx4)(0.0f);
#pragma unroll
    for (int ks = 0; ks < 2; ++ks)
#pragma unroll
        for (int mi = 0; mi < 4; ++mi)
#pragma unroll
            for (int ni = 0; ni < 4; ++ni)
                acc[mi][ni] = __builtin_amdgcn_mfma_f32_16x16x32_bf16(qf[mi][ks], kf[ni][ks], acc[mi][ni], 0, 0, 0);

    // ---- mask + scale, row softmax (row = mi*16+hi*4+r, col = ni*16+lr) ----
#pragma unroll
    for (int mi = 0; mi < 4; ++mi)
#pragma unroll
        for (int ni = 0; ni < 4; ++ni) {
            const int col = ni * 16 + lr;
#pragma unroll
            for (int r = 0; r < 4; ++r)
                acc[mi][ni][r] = (col < 49) ? acc[mi][ni][r] * 0.125f : -1e30f;
        }
#pragma unroll
    for (int mi = 0; mi < 4; ++mi) {
#pragma unroll
        for (int r = 0; r < 4; ++r) {
            float mx = fmaxf(fmaxf(acc[mi][0][r], acc[mi][1][r]), fmaxf(acc[mi][2][r], acc[mi][3][r]));
#pragma unroll
            for (int off = 8; off; off >>= 1) mx = fmaxf(mx, __shfl_xor(mx, off));
            float e0 = expf(acc[mi][0][r] - mx), e1 = expf(acc[mi][1][r] - mx);
            float e2 = expf(acc[mi][2][r] - mx), e3 = expf(acc[mi][3][r] - mx);
            float sum = e0 + e1 + e2 + e3;
#pragma unroll
            for (int off = 8; off; off >>= 1) sum += __shfl_xor(sum, off);
            const float inv = 1.0f / sum;
            const int row = mi * 16 + hi * 4 + r;
            Ps[row * 72 + 0  + lr] = f2bf(e0 * inv);
            Ps[row * 72 + 16 + lr] = f2bf(e1 * inv);
            Ps[row * 72 + 32 + lr] = f2bf(e2 * inv);
            Ps[row * 72 + 48 + lr] = f2bf(e3 * inv);
        }
    }

    // ---- O = P*V via LDS fragments ----
    floatx4 oac[4][4];
#pragma unroll
    for (int i = 0; i < 4; ++i)
#pragma unroll
        for (int j = 0; j < 4; ++j) oac[i][j] = (floatx4)(0.0f);
#pragma unroll
    for (int ks = 0; ks < 2; ++ks) {
        short8 pf[4], vf[4];
        const int p0 = ks * 32 + hi * 8;
#pragma unroll
        for (int mi = 0; mi < 4; ++mi)
            pf[mi] = *(const short8*)(Ps + (mi * 16 + lr) * 72 + p0);
#pragma unroll
        for (int ni = 0; ni < 4; ++ni) {
            const int cc = ni * 16 + lr;
            vf[ni] = *(const short8*)(vsT + cc * 72 + (p0 ^ ((cc >> 3) << 3)));
        }
#pragma unroll
        for (int mi = 0; mi < 4; ++mi)
#pragma unroll
            for (int ni = 0; ni < 4; ++ni)
                oac[mi][ni] = __builtin_amdgcn_mfma_f32_16x16x32_bf16(pf[mi], vf[ni], oac[mi][ni], 0, 0, 0);
    }

    // ---- store rows < 49 ----
#pragma unroll
    for (int mi = 0; mi < 4; ++mi)
#pragma unroll
        for (int r = 0; r < 4; ++r) {
            const int row = mi * 16 + hi * 4 + r;
            if (row >= 49) continue;
            const size_t ob = ((size_t)((b * 49 + row) * 4 + m)) * 768 + h * 64;
#pragma unroll
            for (int ni = 0; ni < 4; ++ni)
                xn[ob + ni * 16 + lr] = f2bf(oac[mi][ni][r]);
        }
}

// ---------------------------------------------------------------------------
// Attention along m (seq=4) + mix fusion. Block = (b_local, n), 256 thr.
// Vectorized staging (ushort8 -> float4 LDS, stride 68). In-place xn update.
// ---------------------------------------------------------------------------
__global__ __launch_bounds__(256) void attn_m_kernel(const unsigned short* __restrict__ qkv,
                                                     const float* __restrict__ mixp,
                                                     unsigned short* __restrict__ xn) {
    __shared__ __attribute__((aligned(16))) float qs[4 * 12 * 68], ks[4 * 12 * 68], vs[4 * 12 * 68];
    __shared__ float as[192];
    const int tid = threadIdx.x;
    const size_t tbase = (size_t)blockIdx.x * 4;
    const int n = blockIdx.x % 49;   // global n (independent of batch)

    for (int c = tid; c < 384; c += 256) {   // 384 = 4m x 12h x 8 cc-chunks
        const int mq = c / 96;
        const int rem = c - mq * 96;
        const int hh = rem >> 3, cc0 = (rem & 7) << 3;
        const size_t base = (tbase + mq) * 2304 + hh * 64 + cc0;
        const short8 qv = *(const short8*)(qkv + base);
        const short8 kv = *(const short8*)(qkv + base + 768);
        const short8 vv = *(const short8*)(qkv + base + 1536);
        const int slot = (mq * 12 + hh) * 68 + cc0;
        float4 f;
        f.x = bf2f((unsigned short)qv[0]); f.y = bf2f((unsigned short)qv[1]);
        f.z = bf2f((unsigned short)qv[2]); f.w = bf2f((unsigned short)qv[3]);
        *(float4*)(qs + slot) = f;
        f.x = bf2f((unsigned short)qv[4]); f.y = bf2f((unsigned short)qv[5]);
        f.z = bf2f((unsigned short)qv[6]); f.w = bf2f((unsigned short)qv[7]);
        *(float4*)(qs + slot + 4) = f;
        f.x = bf2f((unsigned short)kv[0]); f.y = bf2f((unsigned short)kv[1]);
        f.z = bf2f((unsigned short)kv[2]); f.w = bf2f((unsigned short)kv[3]);
        *(float4*)(ks + slot) = f;
        f.x = bf2f((unsigned short)kv[4]); f.y = bf2f((unsigned short)kv[5]);
        f.z = bf2f((unsigned short)kv[6]); f.w = bf2f((unsigned short)kv[7]);
        *(float4*)(ks + slot + 4) = f;
        f.x = bf2f((unsigned short)vv[0]); f.y = bf2f((unsigned short)vv[1]);
        f.z = bf2f((unsigned short)vv[2]); f.w = bf2f((unsigned short)vv[3]);
        *(float4*)(vs + slot) = f;
        f.x = bf2f((unsigned short)vv[4]); f.y = bf2f((unsigned short)vv[5]);
        f.z = bf2f((unsigned short)vv[6]); f.w = bf2f((unsigned short)vv[7]);
        *(float4*)(vs + slot + 4) = f;
    }
    __syncthreads();

    if (tid < 192) {  // one score (head, m, p) per thread
        const int hh = tid >> 4, m = (tid >> 2) & 3, p = tid & 3;
        const float* q = qs + (m * 12 + hh) * 68;
        const float* k = ks + (p * 12 + hh) * 68;
        float s = 0.f;
#pragma unroll
        for (int cc = 0; cc < 64; ++cc) s += q[cc] * k[cc];
        as[tid] = s * 0.125f;
    }
    __syncthreads();
    if (tid < 48) {  // softmax over p=4 for (head, m)
        float* a = as + tid * 4;
        float mx = fmaxf(fmaxf(a[0], a[1]), fmaxf(a[2], a[3]));
        float e0 = expf(a[0] - mx), e1 = expf(a[1] - mx), e2 = expf(a[2] - mx), e3 = expf(a[3] - mx);
        float inv = 1.f / (e0 + e1 + e2 + e3);
        a[0] = e0 * inv; a[1] = e1 * inv; a[2] = e2 * inv; a[3] = e3 * inv;
    }
    __syncthreads();

    float w0[4], w1[4];
#pragma unroll
    for (int m = 0; m < 4; ++m) {
        const float m0 = mixp[(n * 4 + m) * 2], m1 = mixp[(n * 4 + m) * 2 + 1];
        const float mx = fmaxf(m0, m1);
        const float e0 = expf(m0 - mx), e1 = expf(m1 - mx);
        w0[m] = e0 / (e0 + e1);
        w1[m] = 1.0f - w0[m];
    }

    for (int o = tid; o < 3072; o += 256) {
        const int cc = o & 63, m = (o >> 6) & 3, hh = o >> 8;
        const float* a = as + hh * 16 + m * 4;
        float r = a[0] * vs[(0 * 12 + hh) * 68 + cc] + a[1] * vs[(1 * 12 + hh) * 68 + cc]
                + a[2] * vs[(2 * 12 + hh) * 68 + cc] + a[3] * vs[(3 * 12 + hh) * 68 + cc];
        const size_t oidx = (tbase + m) * 768 + hh * 64 + cc;
        const float vn = bf2f(xn[oidx]);
        xn[oidx] = f2bf(vn * w0[m] + r * w1[m]);
    }
}

// ---------------------------------------------------------------------------
extern "C" void kernel_launch(void* const* d_in, const int* in_sizes, int n_in,
                              void* d_out, int out_size, void* d_ws, size_t ws_size,
                              hipStream_t stream) {
    const float* x      = (const float*)d_in[0];
    const float* ln1_g  = (const float*)d_in[1];
    const float* ln1_b  = (const float*)d_in[2];
    const float* w_qkv  = (const float*)d_in[3];
    const float* w_proj = (const float*)d_in[4];
    const float* b_proj = (const float*)d_in[5];
    const float* mixp   = (const float*)d_in[6];
    const float* ln2_g  = (const float*)d_in[7];
    const float* ln2_b  = (const float*)d_in[8];
    const float* w_fc1  = (const float*)d_in[9];
    const float* b_fc1  = (const float*)d_in[10];
    const float* w_fc2  = (const float*)d_in[11];
    const float* b_fc2  = (const float*)d_in[12];
    float* out = (float*)d_out;

    char* ws = (char*)d_ws;
    unsigned short* wqkv_bf  = (unsigned short*)(ws);                  //  3,538,944
    unsigned short* wproj_bf = (unsigned short*)(ws + 3538944);        //  1,179,648
    unsigned short* wfc1_bf  = (unsigned short*)(ws + 4718592);        //  4,718,592
    unsigned short* wfc2_bf  = (unsigned short*)(ws + 9437184);        //  4,718,592

    // adaptive chunking (proven: ws >= 110.5 MB -> CB=64, kept for safety)
    int CB = 64;
    while (CB > 1 && 14155776ull + (size_t)CB * 196 * 7680 > ws_size) CB >>= 1;
    const int nch = 256 / CB;
    const int TC = CB * 196;
    const int rowT = (TC + 127) >> 7;
    unsigned short* xbuf  = (unsigned short*)(ws + 14155776);
    unsigned short* qkv_c = (unsigned short*)(ws + 14155776 + (size_t)TC * 1536);

    dim3 blk(256);
    cvt4_kernel<<<6912, blk, 0, stream>>>((const float4*)w_qkv, (const float4*)w_proj,
                                          (const float4*)w_fc1, (const float4*)w_fc2,
                                          (ushort4*)wqkv_bf, (ushort4*)wproj_bf,
                                          (ushort4*)wfc1_bf, (ushort4*)wfc2_bf);

    for (int i = 0; i < nch; ++i) {
        const size_t r0 = (size_t)i * TC;
        const float* xc = x + r0 * 768;
        float* x2c = out + r0 * 768;

        ln_kernel<<<TC, dim3(192), 0, stream>>>(xc, ln1_g, ln1_b, xbuf);
        gemm_bt<0><<<rowT * 18, blk, 0, stream>>>(xbuf, wqkv_bf, nullptr, nullptr, qkv_c, nullptr, TC, 2304, 768);
        attn_n_kernel<<<CB * 12, blk, 0, stream>>>(qkv_c, xbuf);          // 4 heads/block
        attn_m_kernel<<<CB * 49, blk, 0, stream>>>(qkv_c, mixp, xbuf);    // fuses mix
        gemm_bt<1><<<rowT * 6, blk, 0, stream>>>(xbuf, wproj_bf, b_proj, xc, nullptr, x2c, TC, 768, 768);
        ln_kernel<<<TC, dim3(192), 0, stream>>>(x2c, ln2_g, ln2_b, xbuf);
        gemm_bt<2><<<rowT * 24, blk, 0, stream>>>(xbuf, wfc1_bf, b_fc1, nullptr, qkv_c, nullptr, TC, 3072, 768);
        gemm_bt<1><<<rowT * 6, blk, 0, stream>>>(qkv_c, wfc2_bf, b_fc2, x2c, nullptr, x2c, TC, 768, 3072);
    }
}